// Round 1
// 603.647 us; speedup vs baseline: 1.0252x; 1.0252x over previous
//
#include <hip/hip_runtime.h>
#include <stdint.h>

#define D_IN 512
#define D_HID 256

typedef __attribute__((ext_vector_type(8))) short bf16x8;
typedef __attribute__((ext_vector_type(4))) float f32x4;

__device__ __forceinline__ float b2f(unsigned short u) {
    union { float f; uint32_t i; } x; x.i = ((uint32_t)u) << 16; return x.f;
}
__device__ __forceinline__ unsigned short f2b(float f) {
    union { float f; uint32_t i; } x; x.f = f;
    uint32_t i = x.i;
    uint32_t r = (i + 0x7FFFu + ((i >> 16) & 1u)) >> 16;
    return (unsigned short)r;
}

// async global->LDS 16B copy; dest is wave-uniform base + lane*16 (HW rule)
__device__ __forceinline__ void async_copy16(const unsigned short* g, unsigned short* lds) {
    __builtin_amdgcn_global_load_lds((const __attribute__((address_space(1))) unsigned int*)g,
                                     (__attribute__((address_space(3))) unsigned int*)lds,
                                     16, 0, 0);
}

// ---------- dtype detector (parallel): flag|=1 if raw bits are float32 ----------
__global__ __launch_bounds__(256) void detect_dtype_kernel(const ushort4* __restrict__ raw,
                                                           int n4, int* __restrict__ flag) {
    int i = blockIdx.x * blockDim.x + threadIdx.x;
    int hit = 0;
    if (i < n4) {
        ushort4 u = raw[i];
        hit = ((((u.x >> 7) & 0xFF) == 0xFF) || (((u.y >> 7) & 0xFF) == 0xFF) ||
               (((u.z >> 7) & 0xFF) == 0xFF) || (((u.w >> 7) & 0xFF) == 0xFF)) ? 1 : 0;
    }
    unsigned long long b = __ballot(hit);
    if ((threadIdx.x & 63) == 0 && b != 0ULL) atomicOr(flag, 1);
}

// ---------- x cast to bf16 (f32 -> RNE round; bf16 -> copy) ----------
__global__ __launch_bounds__(256) void xcast_kernel(const void* __restrict__ X,
        unsigned short* __restrict__ xh, int n4, const int* __restrict__ flag) {
    int i = blockIdx.x * blockDim.x + threadIdx.x;   // group of 4 elems
    if (i >= n4) return;
    ushort4 o;
    if (*flag != 0) {
        float4 v = ((const float4*)X)[i];
        o.x = f2b(v.x); o.y = f2b(v.y); o.z = f2b(v.z); o.w = f2b(v.w);
    } else {
        o = ((const ushort4*)X)[i];
    }
    ((ushort4*)xh)[i] = o;
}

// ---------- degree histogram ----------
__global__ void hist_kernel(const int* __restrict__ dst, int* __restrict__ counts, int E) {
    int e = blockIdx.x * blockDim.x + threadIdx.x;
    if (e < E) atomicAdd(&counts[dst[e]], 1);
}

// ---------- parallel scan P1/P2/P3 ----------
__global__ __launch_bounds__(256) void partial_sum_kernel(const int* __restrict__ counts,
        int* __restrict__ partial, int n) {
    __shared__ int sh[4];
    int b = blockIdx.x;
    int lane = threadIdx.x & 63, wv = threadIdx.x >> 6;
    int s = 0;
    for (int j = threadIdx.x; j < 1024; j += 256) {
        int i = b * 1024 + j;
        s += (i < n) ? counts[i] : 0;
    }
#pragma unroll
    for (int off = 32; off > 0; off >>= 1) s += __shfl_down(s, off, 64);
    if (lane == 0) sh[wv] = s;
    __syncthreads();
    if (threadIdx.x == 0) partial[b] = sh[0] + sh[1] + sh[2] + sh[3];
}

__global__ void scan_partials_kernel(int* __restrict__ partial, int nb,
                                     int* __restrict__ indptr, int N) {
    int lane = threadIdx.x & 63;
    int orig = (lane < nb) ? partial[lane] : 0;
    int v = orig;
#pragma unroll
    for (int off = 1; off < 64; off <<= 1) {
        int u = __shfl(v, lane - off, 64);
        if (lane >= off) v += u;
    }
    int tot = __shfl(v, nb - 1, 64);
    if (lane < nb) partial[lane] = v - orig;
    if (lane == 0) indptr[N] = tot;
}

__global__ __launch_bounds__(1024) void scan_chunk_kernel(const int* __restrict__ counts,
        const int* __restrict__ partial, int* __restrict__ indptr, int* __restrict__ cursor,
        float* __restrict__ dinv, int n) {
    __shared__ int sh[1024];
    int b = blockIdx.x;
    int i = b * 1024 + threadIdx.x;
    int v = (i < n) ? counts[i] : 0;
    sh[threadIdx.x] = v;
    __syncthreads();
    for (int off = 1; off < 1024; off <<= 1) {
        int t = (threadIdx.x >= off) ? sh[threadIdx.x - off] : 0;
        __syncthreads();
        sh[threadIdx.x] += t;
        __syncthreads();
    }
    if (i < n) {
        int e = partial[b] + sh[threadIdx.x] - v;
        indptr[i] = e;
        cursor[i] = e;
        dinv[i] = rsqrtf((float)(v + 1));
    }
}

// scatter also emits csr_dst (node id per CSR slot) and csr_eid (original edge id)
// so downstream kernels can walk edges in dst-sorted order.
__global__ void scatter_kernel(const int* __restrict__ src, const int* __restrict__ dst,
                               int* __restrict__ cursor, int* __restrict__ csr_src,
                               int* __restrict__ csr_dst, int* __restrict__ csr_eid, int E) {
    int e = blockIdx.x * blockDim.x + threadIdx.x;
    if (e < E) {
        int d = dst[e];
        int pos = atomicAdd(&cursor[d], 1);
        csr_src[pos] = src[e];
        csr_dst[pos] = d;
        csr_eid[pos] = e;
    }
}

// ---------- W transpose to bf16: W[K][256] -> WT[256][K] ----------
__global__ void wT_kernel(const void* __restrict__ W, unsigned short* __restrict__ WT,
                          int K, const int* __restrict__ flag) {
    int idx = blockIdx.x * blockDim.x + threadIdx.x;
    if (idx >= K * 256) return;
    int k = idx >> 8;
    int n = idx & 255;
    float v = (*flag != 0) ? ((const float*)W)[idx] : b2f(((const unsigned short*)W)[idx]);
    WT[n * K + k] = f2b(v);
}

// ---------- pure-bf16 MFMA GEMM: C[M,256] = A[M,K] @ W[K,256] (A,WT bf16) ----------
// block = 256 thr / 4 waves; tile 64 rows x 256 cols; wave w: cols [64w, 64w+64).
// BK=64: A[64][64] staged via global_load_lds (16B/lane). LDS layout row-major 128B rows
// with 16B-segment rotation seg' = (seg + row) & 7 -> conflict-free ds_read_b128.
// Frag layout (validated r4-r9): A lane m=lane&15 row, k=grp*8; B = WT row (ct*16+n0);
// C/D: col = lane&15, row = grp*4 + reg.
template<int K>
__global__ __launch_bounds__(256) void gemm_bf16(const unsigned short* __restrict__ A,
        const unsigned short* __restrict__ WT, unsigned short* __restrict__ C, int M) {
    __shared__ unsigned short As[64 * 64];    // 8 KB
    int t = threadIdx.x;
    int lane = t & 63, wv = t >> 6;
    int n0 = lane & 15, grp = lane >> 4;
    int row0 = blockIdx.x * 64;

    // staging coords: wave wv, issue j covers rows [wv*16 + j*8, +8), lane l -> row +l/8, seg' l%8
    int srow = wv * 16 + (lane >> 3);         // + j*8 added per issue
    int segp = lane & 7;

    f32x4 acc[4][4];
#pragma unroll
    for (int rt = 0; rt < 4; ++rt)
#pragma unroll
        for (int ct = 0; ct < 4; ++ct) acc[rt][ct] = (f32x4){0.f, 0.f, 0.f, 0.f};

    for (int kk = 0; kk < K / 64; ++kk) {
        int kof = kk * 64;
#pragma unroll
        for (int j = 0; j < 2; ++j) {
            int row = srow + j * 8;
            int s = (segp - row) & 7;                       // global 16B-seg for this dest slot
            const unsigned short* g = A + (size_t)min(row0 + row, M - 1) * K + kof + s * 8;
            async_copy16(g, As + wv * 1024 + j * 512);      // ushort units: 1024 = 2KB/wave
        }
        __syncthreads();
        // W fragments: 8 x 16B from L2-hot WT
        bf16x8 bw[4][2];
#pragma unroll
        for (int ct = 0; ct < 4; ++ct)
#pragma unroll
            for (int h = 0; h < 2; ++h)
                bw[ct][h] = *(const bf16x8*)(WT + (size_t)((wv * 4 + ct) * 16 + n0) * K
                                             + kof + h * 32 + grp * 8);
        // A fragments from LDS + MFMA
#pragma unroll
        for (int rt = 0; rt < 4; ++rt) {
            int r = rt * 16 + n0;
#pragma unroll
            for (int h = 0; h < 2; ++h) {
                int sp = (h * 4 + grp + r) & 7;
                bf16x8 a = *(const bf16x8*)(As + r * 64 + sp * 8);
#pragma unroll
                for (int ct = 0; ct < 4; ++ct)
                    acc[rt][ct] = __builtin_amdgcn_mfma_f32_16x16x32_bf16(a, bw[ct][h],
                                                                          acc[rt][ct], 0, 0, 0);
            }
        }
        __syncthreads();
    }
#pragma unroll
    for (int rt = 0; rt < 4; ++rt) {
#pragma unroll
        for (int ct = 0; ct < 4; ++ct) {
#pragma unroll
            for (int reg = 0; reg < 4; ++reg) {
                int row = row0 + rt * 16 + grp * 4 + reg;
                if (row < M)
                    C[(size_t)row * 256 + (wv * 4 + ct) * 16 + n0] = f2b(acc[rt][ct][reg]);
            }
        }
    }
}

// ---------- GCN aggregation (bf16 h in, bf16 out, f32 accum) ----------
__global__ __launch_bounds__(256) void aggregate_kernel(const unsigned short* __restrict__ h,
        const int* __restrict__ indptr, const int* __restrict__ csr_src,
        const float* __restrict__ dinv, const void* __restrict__ bias,
        unsigned short* __restrict__ out, int n, int do_relu, const int* __restrict__ flag) {
    int wave = threadIdx.x >> 6;
    int lane = threadIdx.x & 63;
    int v = blockIdx.x * 4 + wave;
    if (v >= n) return;
    int beg = indptr[v];
    int end = indptr[v + 1];
    float dv = dinv[v];
    ushort4 hv = *(const ushort4*)(h + (size_t)v * 256 + lane * 4);
    float a0 = dv * b2f(hv.x), a1 = dv * b2f(hv.y), a2 = dv * b2f(hv.z), a3 = dv * b2f(hv.w);
    for (int e = beg; e < end; ++e) {
        int s = csr_src[e];
        float w = dinv[s];
        ushort4 hs = *(const ushort4*)(h + (size_t)s * 256 + lane * 4);
        a0 += w * b2f(hs.x); a1 += w * b2f(hs.y); a2 += w * b2f(hs.z); a3 += w * b2f(hs.w);
    }
    float4 bb;
    if (*flag != 0) {
        bb = *(const float4*)((const float*)bias + lane * 4);
    } else {
        ushort4 bu = *(const ushort4*)((const unsigned short*)bias + lane * 4);
        bb.x = b2f(bu.x); bb.y = b2f(bu.y); bb.z = b2f(bu.z); bb.w = b2f(bu.w);
    }
    float o0 = dv * a0 + bb.x;
    float o1 = dv * a1 + bb.y;
    float o2 = dv * a2 + bb.z;
    float o3 = dv * a3 + bb.w;
    if (do_relu) {
        o0 = fmaxf(o0, 0.f); o1 = fmaxf(o1, 0.f); o2 = fmaxf(o2, 0.f); o3 = fmaxf(o3, 0.f);
    }
    ushort4 ov;
    ov.x = f2b(o0); ov.y = f2b(o1); ov.z = f2b(o2); ov.w = f2b(o3);
    *(ushort4*)(out + (size_t)v * 256 + lane * 4) = ov;
}

// ---------- edge scoring via MFMA: 16 CSR-ordered edges per wave ----------
// Walking edges in dst-sorted (CSR) order makes the h[dst] gather cache-resident:
// avg degree = 16, so a 16-edge wave touches ~1-2 distinct dst rows (L1/L2 broadcast)
// instead of 16 random rows. h[src] stays a random gather. Output is scattered
// through csr_eid back to original edge order (4B scatter, same class as csr writes).
__global__ __launch_bounds__(256) void edge_score_mfma(const unsigned short* __restrict__ h,
        const int* __restrict__ csr_src, const int* __restrict__ csr_dst,
        const int* __restrict__ csr_eid,
        void* __restrict__ out, int E, const int* __restrict__ flag) {
    int lane = threadIdx.x & 63;
    int wv = threadIdx.x >> 6;
    int base = (blockIdx.x * 4 + wv) * 16;
    if (base >= E) return;
    int m = lane & 15, grp = lane >> 4;
    int e = base + m;
    int ec = min(e, E - 1);
    int s = csr_src[ec], d = csr_dst[ec];
    int eid = csr_eid[ec];
    const unsigned short* hs = h + (size_t)s * 256 + grp * 8;
    const unsigned short* hd = h + (size_t)d * 256 + grp * 8;
    f32x4 acc = {0.f, 0.f, 0.f, 0.f};
#pragma unroll
    for (int kk = 0; kk < 8; ++kk) {
        bf16x8 a = *(const bf16x8*)(hs + kk * 32);
        bf16x8 b = *(const bf16x8*)(hd + kk * 32);
        acc = __builtin_amdgcn_mfma_f32_16x16x32_bf16(a, b, acc, 0, 0, 0);
    }
    int reg = m - grp * 4;
    if (reg >= 0 && reg < 4 && e < E) {
        float p = (reg == 0) ? acc[0] : (reg == 1) ? acc[1] : (reg == 2) ? acc[2] : acc[3];
        float prob = 1.f / (1.f + __expf(-p));
        if (*flag != 0)
            ((float*)out)[eid] = prob;
        else
            ((unsigned short*)out)[eid] = f2b(prob);
    }
}

extern "C" void kernel_launch(void* const* d_in, const int* in_sizes, int n_in,
                              void* d_out, int out_size, void* d_ws, size_t ws_size,
                              hipStream_t stream) {
    const void* x  = d_in[0];
    const int* edge_index = (const int*)d_in[1];
    const void* W1 = d_in[2];
    const void* b1 = d_in[3];
    const void* W2 = d_in[4];
    const void* b2 = d_in[5];

    const int N = in_sizes[0] / D_IN;   // 50000
    const int E = in_sizes[1] / 2;      // 800000
    const int* src = edge_index;
    const int* dst = edge_index + E;

    char* ws = (char*)d_ws;
    size_t off = 0;
    auto alloc = [&](size_t bytes) {
        char* p = ws + off;
        off = (off + bytes + 255) & ~(size_t)255;
        return p;
    };
    int* flag     = (int*)alloc(256);
    float* dinv   = (float*)alloc((size_t)N * 4);
    int* counts   = (int*)alloc((size_t)N * 4);
    int* indptr   = (int*)alloc((size_t)(N + 1) * 4);
    int* cursor   = (int*)alloc((size_t)N * 4);
    int* partial  = (int*)alloc(64 * 4);
    int* csr_src  = (int*)alloc((size_t)E * 4);
    int* csr_dst  = (int*)alloc((size_t)E * 4);
    int* csr_eid  = (int*)alloc((size_t)E * 4);
    unsigned short* W1T = (unsigned short*)alloc((size_t)D_IN * 256 * 2);
    unsigned short* W2T = (unsigned short*)alloc((size_t)D_HID * 256 * 2);
    unsigned short* xh  = (unsigned short*)alloc((size_t)N * D_IN * 2);   // 51.2 MB
    unsigned short* hA  = (unsigned short*)alloc((size_t)N * 256 * 2);    // 25.6 MB
    unsigned short* hB  = (unsigned short*)alloc((size_t)N * 256 * 2);    // 25.6 MB

    const int nb = (N + 1023) / 1024;   // 49 <= 64

    hipMemsetAsync(flag, 0, 4, stream);
    hipMemsetAsync(counts, 0, (size_t)N * 4, stream);
    detect_dtype_kernel<<<64, 256, 0, stream>>>((const ushort4*)x, 16384, flag);
    xcast_kernel<<<(N * D_IN / 4 + 255) / 256, 256, 0, stream>>>(x, xh, N * D_IN / 4, flag);
    hist_kernel<<<(E + 255) / 256, 256, 0, stream>>>(dst, counts, E);
    partial_sum_kernel<<<nb, 256, 0, stream>>>(counts, partial, N);
    scan_partials_kernel<<<1, 64, 0, stream>>>(partial, nb, indptr, N);
    scan_chunk_kernel<<<nb, 1024, 0, stream>>>(counts, partial, indptr, cursor, dinv, N);
    scatter_kernel<<<(E + 255) / 256, 256, 0, stream>>>(src, dst, cursor, csr_src, csr_dst, csr_eid, E);
    wT_kernel<<<(D_IN * 256 + 255) / 256, 256, 0, stream>>>(W1, W1T, D_IN, flag);
    wT_kernel<<<(D_HID * 256 + 255) / 256, 256, 0, stream>>>(W2, W2T, D_HID, flag);

    int ggrid = (N + 63) / 64;
    gemm_bf16<D_IN><<<ggrid, 256, 0, stream>>>(xh, W1T, hA, N);
    aggregate_kernel<<<(N + 3) / 4, 256, 0, stream>>>(hA, indptr, csr_src, dinv, b1, hB, N, 1, flag);
    gemm_bf16<D_HID><<<ggrid, 256, 0, stream>>>(hB, W2T, hA, N);
    aggregate_kernel<<<(N + 3) / 4, 256, 0, stream>>>(hA, indptr, csr_src, dinv, b2, hB, N, 0, flag);
    edge_score_mfma<<<(E + 63) / 64, 256, 0, stream>>>(hB, csr_src, csr_dst, csr_eid, d_out, E, flag);
}

// Round 2
// 542.698 us; speedup vs baseline: 1.1404x; 1.1123x over previous
//
#include <hip/hip_runtime.h>
#include <stdint.h>

#define D_IN 512
#define D_HID 256

typedef __attribute__((ext_vector_type(8))) short bf16x8;
typedef __attribute__((ext_vector_type(8))) unsigned short u16x8;
typedef __attribute__((ext_vector_type(4))) float f32x4;

__device__ __forceinline__ float b2f(unsigned short u) {
    union { float f; uint32_t i; } x; x.i = ((uint32_t)u) << 16; return x.f;
}
__device__ __forceinline__ unsigned short f2b(float f) {
    union { float f; uint32_t i; } x; x.f = f;
    uint32_t i = x.i;
    uint32_t r = (i + 0x7FFFu + ((i >> 16) & 1u)) >> 16;
    return (unsigned short)r;
}

// async global->LDS 16B copy; dest is wave-uniform base + lane*16 (HW rule)
__device__ __forceinline__ void async_copy16(const unsigned short* g, unsigned short* lds) {
    __builtin_amdgcn_global_load_lds((const __attribute__((address_space(1))) unsigned int*)g,
                                     (__attribute__((address_space(3))) unsigned int*)lds,
                                     16, 0, 0);
}

// ---------- dtype detector (parallel): flag|=1 if raw bits are float32 ----------
__global__ __launch_bounds__(256) void detect_dtype_kernel(const ushort4* __restrict__ raw,
                                                           int n4, int* __restrict__ flag) {
    int i = blockIdx.x * blockDim.x + threadIdx.x;
    int hit = 0;
    if (i < n4) {
        ushort4 u = raw[i];
        hit = ((((u.x >> 7) & 0xFF) == 0xFF) || (((u.y >> 7) & 0xFF) == 0xFF) ||
               (((u.z >> 7) & 0xFF) == 0xFF) || (((u.w >> 7) & 0xFF) == 0xFF)) ? 1 : 0;
    }
    unsigned long long b = __ballot(hit);
    if ((threadIdx.x & 63) == 0 && b != 0ULL) atomicOr(flag, 1);
}

// ---------- x cast to bf16 (f32 -> RNE round; bf16 -> copy) ----------
__global__ __launch_bounds__(256) void xcast_kernel(const void* __restrict__ X,
        unsigned short* __restrict__ xh, int n4, const int* __restrict__ flag) {
    int i = blockIdx.x * blockDim.x + threadIdx.x;   // group of 4 elems
    if (i >= n4) return;
    ushort4 o;
    if (*flag != 0) {
        float4 v = ((const float4*)X)[i];
        o.x = f2b(v.x); o.y = f2b(v.y); o.z = f2b(v.z); o.w = f2b(v.w);
    } else {
        o = ((const ushort4*)X)[i];
    }
    ((ushort4*)xh)[i] = o;
}

// ---------- degree histogram ----------
__global__ void hist_kernel(const int* __restrict__ dst, int* __restrict__ counts, int E) {
    int e = blockIdx.x * blockDim.x + threadIdx.x;
    if (e < E) atomicAdd(&counts[dst[e]], 1);
}

// ---------- parallel scan P1/P2/P3 ----------
__global__ __launch_bounds__(256) void partial_sum_kernel(const int* __restrict__ counts,
        int* __restrict__ partial, int n) {
    __shared__ int sh[4];
    int b = blockIdx.x;
    int lane = threadIdx.x & 63, wv = threadIdx.x >> 6;
    int s = 0;
    for (int j = threadIdx.x; j < 1024; j += 256) {
        int i = b * 1024 + j;
        s += (i < n) ? counts[i] : 0;
    }
#pragma unroll
    for (int off = 32; off > 0; off >>= 1) s += __shfl_down(s, off, 64);
    if (lane == 0) sh[wv] = s;
    __syncthreads();
    if (threadIdx.x == 0) partial[b] = sh[0] + sh[1] + sh[2] + sh[3];
}

__global__ void scan_partials_kernel(int* __restrict__ partial, int nb,
                                     int* __restrict__ indptr, int N) {
    int lane = threadIdx.x & 63;
    int orig = (lane < nb) ? partial[lane] : 0;
    int v = orig;
#pragma unroll
    for (int off = 1; off < 64; off <<= 1) {
        int u = __shfl(v, lane - off, 64);
        if (lane >= off) v += u;
    }
    int tot = __shfl(v, nb - 1, 64);
    if (lane < nb) partial[lane] = v - orig;
    if (lane == 0) indptr[N] = tot;
}

__global__ __launch_bounds__(1024) void scan_chunk_kernel(const int* __restrict__ counts,
        const int* __restrict__ partial, int* __restrict__ indptr, int* __restrict__ cursor,
        float* __restrict__ dinv, int n) {
    __shared__ int sh[1024];
    int b = blockIdx.x;
    int i = b * 1024 + threadIdx.x;
    int v = (i < n) ? counts[i] : 0;
    sh[threadIdx.x] = v;
    __syncthreads();
    for (int off = 1; off < 1024; off <<= 1) {
        int t = (threadIdx.x >= off) ? sh[threadIdx.x - off] : 0;
        __syncthreads();
        sh[threadIdx.x] += t;
        __syncthreads();
    }
    if (i < n) {
        int e = partial[b] + sh[threadIdx.x] - v;
        indptr[i] = e;
        cursor[i] = e;
        dinv[i] = rsqrtf((float)(v + 1));
    }
}

// scatter also emits csr_dst (node id per CSR slot) and csr_eid (original edge id)
// so downstream kernels can walk edges in dst-sorted order.
__global__ void scatter_kernel(const int* __restrict__ src, const int* __restrict__ dst,
                               int* __restrict__ cursor, int* __restrict__ csr_src,
                               int* __restrict__ csr_dst, int* __restrict__ csr_eid, int E) {
    int e = blockIdx.x * blockDim.x + threadIdx.x;
    if (e < E) {
        int d = dst[e];
        int pos = atomicAdd(&cursor[d], 1);
        csr_src[pos] = src[e];
        csr_dst[pos] = d;
        csr_eid[pos] = e;
    }
}

// ---------- W transpose to bf16: W[K][256] -> WT[256][K] ----------
__global__ void wT_kernel(const void* __restrict__ W, unsigned short* __restrict__ WT,
                          int K, const int* __restrict__ flag) {
    int idx = blockIdx.x * blockDim.x + threadIdx.x;
    if (idx >= K * 256) return;
    int k = idx >> 8;
    int n = idx & 255;
    float v = (*flag != 0) ? ((const float*)W)[idx] : b2f(((const unsigned short*)W)[idx]);
    WT[n * K + k] = f2b(v);
}

// ---------- pure-bf16 MFMA GEMM: C[M,256] = A[M,K] @ W[K,256] (A,WT bf16) ----------
// block = 256 thr / 4 waves; tile 64 rows x 256 cols; wave w: cols [64w, 64w+64).
// BK=64: A[64][64] staged via global_load_lds (16B/lane). LDS layout row-major 128B rows
// with 16B-segment rotation seg' = (seg + row) & 7 -> conflict-free ds_read_b128.
// Frag layout (validated r4-r9): A lane m=lane&15 row, k=grp*8; B = WT row (ct*16+n0);
// C/D: col = lane&15, row = grp*4 + reg.
template<int K>
__global__ __launch_bounds__(256) void gemm_bf16(const unsigned short* __restrict__ A,
        const unsigned short* __restrict__ WT, unsigned short* __restrict__ C, int M) {
    __shared__ unsigned short As[64 * 64];    // 8 KB
    int t = threadIdx.x;
    int lane = t & 63, wv = t >> 6;
    int n0 = lane & 15, grp = lane >> 4;
    int row0 = blockIdx.x * 64;

    // staging coords: wave wv, issue j covers rows [wv*16 + j*8, +8), lane l -> row +l/8, seg' l%8
    int srow = wv * 16 + (lane >> 3);         // + j*8 added per issue
    int segp = lane & 7;

    f32x4 acc[4][4];
#pragma unroll
    for (int rt = 0; rt < 4; ++rt)
#pragma unroll
        for (int ct = 0; ct < 4; ++ct) acc[rt][ct] = (f32x4){0.f, 0.f, 0.f, 0.f};

    for (int kk = 0; kk < K / 64; ++kk) {
        int kof = kk * 64;
#pragma unroll
        for (int j = 0; j < 2; ++j) {
            int row = srow + j * 8;
            int s = (segp - row) & 7;                       // global 16B-seg for this dest slot
            const unsigned short* g = A + (size_t)min(row0 + row, M - 1) * K + kof + s * 8;
            async_copy16(g, As + wv * 1024 + j * 512);      // ushort units: 1024 = 2KB/wave
        }
        __syncthreads();
        // W fragments: 8 x 16B from L2-hot WT
        bf16x8 bw[4][2];
#pragma unroll
        for (int ct = 0; ct < 4; ++ct)
#pragma unroll
            for (int h = 0; h < 2; ++h)
                bw[ct][h] = *(const bf16x8*)(WT + (size_t)((wv * 4 + ct) * 16 + n0) * K
                                             + kof + h * 32 + grp * 8);
        // A fragments from LDS + MFMA
#pragma unroll
        for (int rt = 0; rt < 4; ++rt) {
            int r = rt * 16 + n0;
#pragma unroll
            for (int h = 0; h < 2; ++h) {
                int sp = (h * 4 + grp + r) & 7;
                bf16x8 a = *(const bf16x8*)(As + r * 64 + sp * 8);
#pragma unroll
                for (int ct = 0; ct < 4; ++ct)
                    acc[rt][ct] = __builtin_amdgcn_mfma_f32_16x16x32_bf16(a, bw[ct][h],
                                                                          acc[rt][ct], 0, 0, 0);
            }
        }
        __syncthreads();
    }
#pragma unroll
    for (int rt = 0; rt < 4; ++rt) {
#pragma unroll
        for (int ct = 0; ct < 4; ++ct) {
#pragma unroll
            for (int reg = 0; reg < 4; ++reg) {
                int row = row0 + rt * 16 + grp * 4 + reg;
                if (row < M)
                    C[(size_t)row * 256 + (wv * 4 + ct) * 16 + n0] = f2b(acc[rt][ct][reg]);
            }
        }
    }
}

// ---------- GCN aggregation (bf16 h in, bf16 out, f32 accum) ----------
// Latency-bound gather -> maximize per-wave MLP:
//  - wave split into two 32-lane halves; each half covers the full 256-dim row
//    at 16 B/lane (dwordx4) and processes alternating edges (2 independent streams)
//  - 2-deep software pipeline per half (row e+4 in flight while accumulating e)
//  => 4 row-loads (2 KB) in flight per wave vs 1 (512 B) before.
// Halves combined with one shfl_xor(32); lanes 0-31 store the row at 16 B/lane.
__global__ __launch_bounds__(256) void aggregate_kernel(const unsigned short* __restrict__ h,
        const int* __restrict__ indptr, const int* __restrict__ csr_src,
        const float* __restrict__ dinv, const void* __restrict__ bias,
        unsigned short* __restrict__ out, int n, int do_relu, const int* __restrict__ flag) {
    int wave = threadIdx.x >> 6;
    int lane = threadIdx.x & 63;
    int half = lane >> 5;       // 0 or 1: which edge stream
    int hl = lane & 31;         // feature block: dims [hl*8, hl*8+8)
    int v = blockIdx.x * 4 + wave;
    if (v >= n) return;
    int beg = indptr[v];
    int end = indptr[v + 1];
    float dv = dinv[v];

    float acc[8];
    if (half == 0) {
        u16x8 hv = *(const u16x8*)(h + (size_t)v * 256 + hl * 8);
#pragma unroll
        for (int i = 0; i < 8; ++i) acc[i] = dv * b2f(hv[i]);
    } else {
#pragma unroll
        for (int i = 0; i < 8; ++i) acc[i] = 0.f;
    }

    // 2-deep pipelined gather over this half's edges (beg+half, step 2)
    int eA = beg + half;
    float w0 = 0.f, w1 = 0.f;
    u16x8 r0, r1;
    if (eA < end) {
        int s = csr_src[eA];
        w0 = dinv[s];
        r0 = *(const u16x8*)(h + (size_t)s * 256 + hl * 8);
    }
    if (eA + 2 < end) {
        int s = csr_src[eA + 2];
        w1 = dinv[s];
        r1 = *(const u16x8*)(h + (size_t)s * 256 + hl * 8);
    }
    for (int e = eA; e < end; e += 2) {
#pragma unroll
        for (int i = 0; i < 8; ++i) acc[i] += w0 * b2f(r0[i]);
        w0 = w1;
        r0 = r1;
        int en = e + 4;
        if (en < end) {
            int s = csr_src[en];
            w1 = dinv[s];
            r1 = *(const u16x8*)(h + (size_t)s * 256 + hl * 8);
        }
    }

    // combine the two edge streams
#pragma unroll
    for (int i = 0; i < 8; ++i) acc[i] += __shfl_xor(acc[i], 32, 64);

    if (half == 0) {
        float bb[8];
        if (*flag != 0) {
            const float* bp = (const float*)bias + hl * 8;
#pragma unroll
            for (int i = 0; i < 8; ++i) bb[i] = bp[i];
        } else {
            const unsigned short* bp = (const unsigned short*)bias + hl * 8;
#pragma unroll
            for (int i = 0; i < 8; ++i) bb[i] = b2f(bp[i]);
        }
        u16x8 ov;
#pragma unroll
        for (int i = 0; i < 8; ++i) {
            float o = dv * acc[i] + bb[i];
            if (do_relu) o = fmaxf(o, 0.f);
            ov[i] = f2b(o);
        }
        *(u16x8*)(out + (size_t)v * 256 + hl * 8) = ov;
    }
}

// ---------- edge scoring via MFMA: 16 CSR-ordered edges per wave ----------
// Walking edges in dst-sorted (CSR) order makes the h[dst] gather cache-resident:
// avg degree = 16, so a 16-edge wave touches ~1-2 distinct dst rows (L1/L2 broadcast)
// instead of 16 random rows. h[src] stays a random gather. Output is scattered
// through csr_eid back to original edge order (4B scatter, same class as csr writes).
__global__ __launch_bounds__(256) void edge_score_mfma(const unsigned short* __restrict__ h,
        const int* __restrict__ csr_src, const int* __restrict__ csr_dst,
        const int* __restrict__ csr_eid,
        void* __restrict__ out, int E, const int* __restrict__ flag) {
    int lane = threadIdx.x & 63;
    int wv = threadIdx.x >> 6;
    int base = (blockIdx.x * 4 + wv) * 16;
    if (base >= E) return;
    int m = lane & 15, grp = lane >> 4;
    int e = base + m;
    int ec = min(e, E - 1);
    int s = csr_src[ec], d = csr_dst[ec];
    int eid = csr_eid[ec];
    const unsigned short* hs = h + (size_t)s * 256 + grp * 8;
    const unsigned short* hd = h + (size_t)d * 256 + grp * 8;
    f32x4 acc = {0.f, 0.f, 0.f, 0.f};
#pragma unroll
    for (int kk = 0; kk < 8; ++kk) {
        bf16x8 a = *(const bf16x8*)(hs + kk * 32);
        bf16x8 b = *(const bf16x8*)(hd + kk * 32);
        acc = __builtin_amdgcn_mfma_f32_16x16x32_bf16(a, b, acc, 0, 0, 0);
    }
    int reg = m - grp * 4;
    if (reg >= 0 && reg < 4 && e < E) {
        float p = (reg == 0) ? acc[0] : (reg == 1) ? acc[1] : (reg == 2) ? acc[2] : acc[3];
        float prob = 1.f / (1.f + __expf(-p));
        if (*flag != 0)
            ((float*)out)[eid] = prob;
        else
            ((unsigned short*)out)[eid] = f2b(prob);
    }
}

extern "C" void kernel_launch(void* const* d_in, const int* in_sizes, int n_in,
                              void* d_out, int out_size, void* d_ws, size_t ws_size,
                              hipStream_t stream) {
    const void* x  = d_in[0];
    const int* edge_index = (const int*)d_in[1];
    const void* W1 = d_in[2];
    const void* b1 = d_in[3];
    const void* W2 = d_in[4];
    const void* b2 = d_in[5];

    const int N = in_sizes[0] / D_IN;   // 50000
    const int E = in_sizes[1] / 2;      // 800000
    const int* src = edge_index;
    const int* dst = edge_index + E;

    char* ws = (char*)d_ws;
    size_t off = 0;
    auto alloc = [&](size_t bytes) {
        char* p = ws + off;
        off = (off + bytes + 255) & ~(size_t)255;
        return p;
    };
    int* flag     = (int*)alloc(256);
    float* dinv   = (float*)alloc((size_t)N * 4);
    int* counts   = (int*)alloc((size_t)N * 4);
    int* indptr   = (int*)alloc((size_t)(N + 1) * 4);
    int* cursor   = (int*)alloc((size_t)N * 4);
    int* partial  = (int*)alloc(64 * 4);
    int* csr_src  = (int*)alloc((size_t)E * 4);
    int* csr_dst  = (int*)alloc((size_t)E * 4);
    int* csr_eid  = (int*)alloc((size_t)E * 4);
    unsigned short* W1T = (unsigned short*)alloc((size_t)D_IN * 256 * 2);
    unsigned short* W2T = (unsigned short*)alloc((size_t)D_HID * 256 * 2);
    unsigned short* xh  = (unsigned short*)alloc((size_t)N * D_IN * 2);   // 51.2 MB
    unsigned short* hA  = (unsigned short*)alloc((size_t)N * 256 * 2);    // 25.6 MB
    unsigned short* hB  = (unsigned short*)alloc((size_t)N * 256 * 2);    // 25.6 MB

    const int nb = (N + 1023) / 1024;   // 49 <= 64

    hipMemsetAsync(flag, 0, 4, stream);
    hipMemsetAsync(counts, 0, (size_t)N * 4, stream);
    detect_dtype_kernel<<<64, 256, 0, stream>>>((const ushort4*)x, 16384, flag);
    xcast_kernel<<<(N * D_IN / 4 + 255) / 256, 256, 0, stream>>>(x, xh, N * D_IN / 4, flag);
    hist_kernel<<<(E + 255) / 256, 256, 0, stream>>>(dst, counts, E);
    partial_sum_kernel<<<nb, 256, 0, stream>>>(counts, partial, N);
    scan_partials_kernel<<<1, 64, 0, stream>>>(partial, nb, indptr, N);
    scan_chunk_kernel<<<nb, 1024, 0, stream>>>(counts, partial, indptr, cursor, dinv, N);
    scatter_kernel<<<(E + 255) / 256, 256, 0, stream>>>(src, dst, cursor, csr_src, csr_dst, csr_eid, E);
    wT_kernel<<<(D_IN * 256 + 255) / 256, 256, 0, stream>>>(W1, W1T, D_IN, flag);
    wT_kernel<<<(D_HID * 256 + 255) / 256, 256, 0, stream>>>(W2, W2T, D_HID, flag);

    int ggrid = (N + 63) / 64;
    gemm_bf16<D_IN><<<ggrid, 256, 0, stream>>>(xh, W1T, hA, N);
    aggregate_kernel<<<(N + 3) / 4, 256, 0, stream>>>(hA, indptr, csr_src, dinv, b1, hB, N, 1, flag);
    gemm_bf16<D_HID><<<ggrid, 256, 0, stream>>>(hB, W2T, hA, N);
    aggregate_kernel<<<(N + 3) / 4, 256, 0, stream>>>(hA, indptr, csr_src, dinv, b2, hB, N, 0, flag);
    edge_score_mfma<<<(E + 63) / 64, 256, 0, stream>>>(hB, csr_src, csr_dst, csr_eid, d_out, E, flag);
}